// Round 9
// baseline (197.109 us; speedup 1.0000x reference)
//
#include <hip/hip_runtime.h>
#include <hip/hip_bf16.h>

// Problem: B=2, S=2048, C=U=1024, H=16, dh=64. I/O FP32.
// 4 dispatches: prep, QKV GEMM (counted-vmcnt double-buffer pipeline),
// flash attention (8-wave blocks = two 4-wave groups, attn12 schedule +
// CARRIED-SCORE SOFTWARE PIPELINE: round r overlaps QK(tile r) with
// softmax+PV(tile r-1) inside each wave; V staged one round behind K),
// LN apply.

typedef __bf16 bf16_t;
typedef __bf16 bf16x8 __attribute__((ext_vector_type(8)));
typedef __bf16 bf16x4 __attribute__((ext_vector_type(4)));
typedef _Float16 f16_t;
typedef _Float16 f16x2 __attribute__((ext_vector_type(2)));
typedef _Float16 f16x4 __attribute__((ext_vector_type(4)));
typedef _Float16 f16x8 __attribute__((ext_vector_type(8)));
typedef float f32x4 __attribute__((ext_vector_type(4)));

constexpr int Bsz = 2;
constexpr int Seq = 2048;
constexpr int Cdim = 1024;   // == U
constexpr int Udim = 1024;
constexpr int Hn = 16;
constexpr int Dh = 64;
constexpr int Mrows = Bsz * Seq;          // 4096
constexpr int PerBatch = Seq * Udim;      // 2^21
constexpr float SCLQ = 0.125f * 1.44269504088896340736f;  // /sqrt(dh) * log2e

#if __has_builtin(__builtin_amdgcn_exp2f)
#define EXP2F(x) __builtin_amdgcn_exp2f(x)
#else
#define EXP2F(x) exp2f(x)
#endif

#define AINL __attribute__((always_inline))
#define BARRIER() __builtin_amdgcn_s_barrier()
#define SCHEDB() __builtin_amdgcn_sched_barrier(0)
#define WAITV4() asm volatile("s_waitcnt vmcnt(4)" ::: "memory")
#define WAITV0() asm volatile("s_waitcnt vmcnt(0)" ::: "memory")

// async global->LDS, 16B per lane; LDS dest = wave-uniform base + lane*16
__device__ __forceinline__ void gload16(const void* g, void* l)
{
    __builtin_amdgcn_global_load_lds(
        (const __attribute__((address_space(1))) void*)g,
        (__attribute__((address_space(3))) void*)l, 16, 0, 0);
}

// pack two f32 -> f16x2 via v_cvt_pkrtz (returns __fp16x2; bit-identical)
__device__ __forceinline__ f16x2 pkrtz(float a, float b)
{
    return __builtin_bit_cast(f16x2, __builtin_amdgcn_cvt_pkrtz(a, b));
}

// ---------------------------------------------------------------- prep
__global__ __launch_bounds__(256)
void prep(const float* __restrict__ X,
          const float* __restrict__ Wq, const float* __restrict__ Wk,
          const float* __restrict__ Wv,
          bf16_t* __restrict__ Xb,
          bf16_t* __restrict__ Tq, bf16_t* __restrict__ Tk,
          bf16_t* __restrict__ Tv, float* __restrict__ stats)
{
    int z = blockIdx.z;
    int tid = threadIdx.x;
    if (z < 3) {
        const float* W = (z == 0) ? Wq : (z == 1) ? Wk : Wv;
        bf16_t* T = (z == 0) ? Tq : (z == 1) ? Tk : Tv;
        __shared__ bf16_t t[64][65];
        int x0 = blockIdx.x * 64, y0 = blockIdx.y * 64;
        int tx = tid & 63, ty = tid >> 6;
        for (int i = ty; i < 64; i += 4)
            t[i][tx] = (bf16_t)W[(size_t)(y0 + i) * Cdim + x0 + tx];
        __syncthreads();
        for (int i = ty; i < 64; i += 4)
            T[(size_t)(x0 + i) * Cdim + y0 + tx] = t[tx][i];
    } else {
        int bi = blockIdx.y * 16 + blockIdx.x;          // 0..255
        if (bi == 0 && tid < 4) stats[tid] = 0.0f;
        const float4* Xv = (const float4*)X;
#pragma unroll
        for (int k = 0; k < 16; k++) {
            int i = bi * 4096 + k * 256 + tid;          // 1M float4 total
            float4 v = Xv[i];
            bf16x4 o = { (bf16_t)v.x, (bf16_t)v.y, (bf16_t)v.z, (bf16_t)v.w };
            *(bf16x4*)(Xb + (size_t)i * 4) = o;
        }
    }
}

// ---------------------------------------------------------------- QKV GEMM
// 128x128 tile, BK=32, double-buffered LDS + counted vmcnt.
// z==0: Q pre-scaled by SCLQ. z==1: K. z==2: V -> Vt[b][h][d][s].
__global__ __launch_bounds__(256)
void gemm_qkv(const bf16_t* __restrict__ X,
              const bf16_t* __restrict__ Wt0, const bf16_t* __restrict__ Wt1,
              const bf16_t* __restrict__ Wt2,
              const float* __restrict__ b0, const float* __restrict__ b1,
              const float* __restrict__ b2,
              f16_t* __restrict__ O0, f16_t* __restrict__ O1, f16_t* __restrict__ O2v)
{
    int z = blockIdx.z;
    const bf16_t* Wt = (z == 0) ? Wt0 : (z == 1) ? Wt1 : Wt2;
    const float* bias = (z == 0) ? b0 : (z == 1) ? b1 : b2;
    float scl = (z == 0) ? SCLQ : 1.0f;

    constexpr int Kd = 1024, Nd = 1024;
    __shared__ __align__(16) bf16_t As[2][4096];
    __shared__ __align__(16) bf16_t Bs[2][4096];

    int tid = threadIdx.x;
    int wave = tid >> 6, lane = tid & 63, quad = lane >> 4, l16 = lane & 15;
    int wm = (wave & 1) * 64, wn = (wave >> 1) * 64;
    int m0 = blockIdx.y * 128, n0 = blockIdx.x * 128;

    f32x4 acc[4][4] = {};

    int e0 = wave * 512 + lane * 8;
    int r0 = e0 >> 5, c0 = e0 & 31;
    int e1 = e0 + 2048;
    int r1 = e1 >> 5, c1 = e1 & 31;
    const bf16_t* Ag = X + (size_t)m0 * Kd;
    const bf16_t* Bg = Wt + (size_t)n0 * Kd;

    auto STG = [&](int nb, int k0) AINL {
        gload16(Ag + (size_t)r0 * Kd + k0 + c0, &As[nb][wave * 512]);
        gload16(Ag + (size_t)r1 * Kd + k0 + c1, &As[nb][2048 + wave * 512]);
        gload16(Bg + (size_t)r0 * Kd + k0 + c0, &Bs[nb][wave * 512]);
        gload16(Bg + (size_t)r1 * Kd + k0 + c1, &Bs[nb][2048 + wave * 512]);
    };

    int kNext = 32;
    auto STEP = [&](int buf, bool doStage) AINL {
        BARRIER();                       // WAR: prev step's readers of buf^1 done
        if (doStage) { STG(buf ^ 1, kNext); kNext += 32; WAITV4(); }
        else WAITV0();
        BARRIER();                       // all waves' current-step loads landed
        SCHEDB();
        bf16x8 af[4], bfr[4];
#pragma unroll
        for (int i = 0; i < 4; i++)
            af[i] = *(const bf16x8*)&As[buf][(wm + i * 16 + l16) * 32 + quad * 8];
#pragma unroll
        for (int i = 0; i < 4; i++)
            bfr[i] = *(const bf16x8*)&Bs[buf][(wn + i * 16 + l16) * 32 + quad * 8];
#pragma unroll
        for (int mt = 0; mt < 4; mt++)
#pragma unroll
            for (int nt = 0; nt < 4; nt++)
                acc[mt][nt] = __builtin_amdgcn_mfma_f32_16x16x32_bf16(
                    af[mt], bfr[nt], acc[mt][nt], 0, 0, 0);
    };

    STG(0, 0);                           // prologue: K-step 0 into buf 0
    for (int it = 0; it < 15; it++) { STEP(0, true); STEP(1, true); }  // steps 0..29
    STEP(0, true);                       // step 30 (stages k=992)
    STEP(1, false);                      // step 31 (no successor)

    if (z < 2) {
        f16_t* Og = (z == 0) ? O0 : O1;
#pragma unroll
        for (int nt = 0; nt < 4; nt++) {
            int col = n0 + wn + nt * 16 + l16;
            float bv = bias[col];
#pragma unroll
            for (int mt = 0; mt < 4; mt++) {
                int row = m0 + wm + mt * 16 + quad * 4;
#pragma unroll
                for (int r = 0; r < 4; r++)
                    Og[(size_t)(row + r) * Nd + col] = (f16_t)((acc[mt][nt][r] + bv) * scl);
            }
        }
    } else {
        int bb = m0 >> 11;
#pragma unroll
        for (int nt = 0; nt < 4; nt++) {
            int col = n0 + wn + nt * 16 + l16;
            float bv = bias[col];
            int h = col >> 6, d = col & 63;
            f16_t* vbase = O2v + (((size_t)(bb * Hn + h) * Dh + d) << 11);
#pragma unroll
            for (int mt = 0; mt < 4; mt++) {
                int row = m0 + wm + mt * 16 + quad * 4;
                int s = row & (Seq - 1);
                f16x4 pk;
#pragma unroll
                for (int r = 0; r < 4; r++) pk[r] = (f16_t)(acc[mt][nt][r] + bv);
                *(f16x4*)(vbase + s) = pk;
            }
        }
    }
}

// ---------------------------------------------------------------- attention
// 512 blocks x 512 threads (two 4-wave groups). attn12 schedule + carried-
// score pipeline. Group0 stream: B tiles 0..qb (diag at qb), then A tiles
// 0..split-1 (split=15-pi). Group1 stream: A tiles split..qa (diag at qa).
// Both run EXACTLY 17 rounds. Round r: {stage K(tau_{r+1}) & V(tau_r);
// QK(tau_r)->stOUT; softmax+PV(tau_{r-1}) from stIN; __syncthreads}.
// QK MFMAs are independent of softmax VALU/trans -> intra-wave pipe
// overlap; V ds_read latency hides under QK. V staged 1 round behind K so
// V(tau_{r-1}) survives consumption (2-buffer lifetime). Group1 epilogue:
// masked softmax+PV on carried scores. Intra-block LDS combine as before.
__global__ __launch_bounds__(512, 4)
void attn15(const f16_t* __restrict__ Q, const f16_t* __restrict__ K,
            const f16_t* __restrict__ Vt, const float* __restrict__ X,
            bf16_t* __restrict__ R, float* __restrict__ stats)
{
    int id = blockIdx.x;
    int c = id & 7;            // XCD slot (4 bh per XCD -> K/V L2-resident)
    int rr = id >> 3;          // 0..63
    int g = rr & 3;
    int pi = rr >> 2;          // 0..15
    int bh = (g << 3) | c;
    int b = bh >> 4, h = bh & 15;
    int qa = 31 - pi, qb = pi, split = 15 - pi;

    int tid = threadIdx.x;
    int grp = tid >> 8;              // 0 / 1
    int w = (tid >> 6) & 3;          // wave within group
    int lane = tid & 63, quad = lane >> 4, l16 = lane & 15;
    size_t bS = (size_t)b * Seq;

    __shared__ __align__(16) char ldsRaw[65600];
    f16_t* KsBase = (f16_t*)(ldsRaw + grp * 32768);
    f16_t* VsBase = (f16_t*)(ldsRaw + grp * 32768 + 16384);
    float* cmbO   = (float*)(ldsRaw + 32768);   // 16KB (aliases grp1 K bufs, dead)
    float* cmbLS  = (float*)(ldsRaw + 49152);   // 256B (aliases grp1 V buf0, dead)
    float* red    = (float*)(ldsRaw + 65536);   // 16 f32

    const f16_t* Kg = K + bS * Udim + h * Dh;
    const f16_t* Vg = Vt + ((size_t)(b * Hn + h)) * Dh * Seq;

    // staging geometry (pre-swizzled global source, rule #21)
    int srow = w * 8 + (lane >> 3);
    int schunk = (lane & 7) ^ ((lane >> 3) & 7);

    int qidxA = qa * 64 + w * 16 + l16;
    int qidxB = qb * 64 + w * 16 + l16;
    const f16_t* QpA = Q + (bS + qidxA) * Udim + h * Dh;
    const f16_t* QpB = Q + (bS + qidxB) * Udim + h * Dh;
    f16x8 qfA[2], qfB[2];
#pragma unroll
    for (int s2 = 0; s2 < 2; s2++) {
        qfA[s2] = *(const f16x8*)(QpA + s2 * 32 + quad * 8);
        qfB[s2] = *(const f16x8*)(QpB + s2 * 32 + quad * 8);
    }

    // lane-constant swizzled read offsets (f16 elements)
    int m = l16 & 7;
    int kO0 = l16 * 64 + ((quad ^ m) << 3);
    int kO1 = l16 * 64 + (((4 + quad) ^ m) << 3);
    int vO[4];
#pragma unroll
    for (int t = 0; t < 4; t++)
        vO[t] = l16 * 64 + (((t * 32 + quad * 8) ^ (m << 4)) >> 1);

    f32x4 OA[4] = {}, OB[4] = {};
    float lsA = 0.0f, lsB = 0.0f;
    f32x4 stX[4], stY[4];

    // group0 tile stream: rounds 0..15 -> B 0..qb then A 0..split-1
    auto tl0 = [&](int rho) AINL -> int { return (rho <= qb) ? rho : rho - qb - 1; };

    auto STAGE_K = [&](int nb, int tl) AINL {
        const f16_t* kp = Kg + (size_t)(tl * 64 + srow) * Udim + schunk * 8;
        f16_t* kd = KsBase + nb * 4096;
        gload16(kp, kd + w * 512);
        gload16(kp + (size_t)32 * Udim, kd + 2048 + w * 512);
    };
    auto STAGE_V = [&](int nb, int tl) AINL {
        const f16_t* vp = Vg + (size_t)srow * Seq + tl * 64 + schunk * 8;
        f16_t* vd = VsBase + nb * 4096;
        gload16(vp, vd + w * 512);
        gload16(vp + (size_t)32 * Seq, vd + 2048 + w * 512);
    };

    // QK of the tile in Kb[buf] into sOUT (sub-tiles t<=tcap)
    auto QK = [&](int buf, const f16x8 (&qf)[2], f32x4 (&sOUT)[4], int tcap) AINL {
        const f16_t* Kb = KsBase + buf * 4096;
#pragma unroll
        for (int t = 0; t < 4; t++) {
            if (t <= tcap) {
                f16x8 kf0 = *(const f16x8*)&Kb[kO0 + t * 1024];
                f16x8 kf1 = *(const f16x8*)&Kb[kO1 + t * 1024];
                f32x4 a = {};
                a = __builtin_amdgcn_mfma_f32_16x16x32_f16(kf0, qf[0], a, 0, 0, 0);
                a = __builtin_amdgcn_mfma_f32_16x16x32_f16(kf1, qf[1], a, 0, 0, 0);
                sOUT[t] = a;
            }
        }
    };

    // softmax + PV of carried scores sIN (tile's V in Vb[vbuf])
    auto SMPV = [&](f32x4 (&sIN)[4], f32x4 (&O)[4], float& ls, bool msk,
                    int kv0, int qidx, int tcap, int vbuf) AINL {
        const f16_t* Vb = VsBase + vbuf * 4096;
#pragma unroll
        for (int t = 0; t < 4; t++) {
            if (t <= tcap) {
                float pv[4];
#pragma unroll
                for (int r2 = 0; r2 < 4; r2++) {
                    float sv = sIN[t][r2];
                    if (msk && (kv0 + t * 16 + quad * 4 + r2 > qidx)) sv = -1e30f;
                    pv[r2] = EXP2F(sv);
                    ls += pv[r2];
                }
                f16x2 lo = pkrtz(pv[0], pv[1]);
                f16x2 hi = pkrtz(pv[2], pv[3]);
                f16x4 pf;
                pf[0] = lo[0]; pf[1] = lo[1]; pf[2] = hi[0]; pf[3] = hi[1];
#pragma unroll
                for (int dt = 0; dt < 4; dt++) {
                    f16x4 vf = *(const f16x4*)&Vb[vO[t] + dt * 1024];
                    O[dt] = __builtin_amdgcn_mfma_f32_16x16x16f16(vf, pf, O[dt], 0, 0, 0);
                }
            }
        }
    };

    // pipelined round r: buf = r&1 (literal at call sites)
    auto ROUND = [&](int r, int buf, f32x4 (&sIN)[4], f32x4 (&sOUT)[4]) AINL {
        // ---- staging (K one tile ahead; V current tile)
        if (grp == 0) {
            if (r <= 14) STAGE_K(buf ^ 1, tl0(r + 1));
            if (r <= 15) STAGE_V(buf ^ 1, tl0(r));
        } else {
            if (r <= 15) STAGE_K(buf ^ 1, split + r + 1);
            STAGE_V(buf ^ 1, split + r);
        }
        // ---- QK(tau_r) -> sOUT
        if (grp == 0) {
            if (r <= 15) {
                if (r <= qb) QK(buf, qfB, sOUT, (r == qb) ? w : 3);
                else         QK(buf, qfA, sOUT, 3);
            }
        } else {
            QK(buf, qfA, sOUT, (r == 16) ? w : 3);
        }
        // ---- softmax + PV (tau_{r-1}) from sIN; its V is in Vb[buf]
        if (r >= 1) {
            if (grp == 0) {
                if (r <= qb)          SMPV(sIN, OB, lsB, false, 0, 0, 3, buf);
                else if (r == qb + 1) SMPV(sIN, OB, lsB, true, qb * 64, qidxB, w, buf);
                else                  SMPV(sIN, OA, lsA, false, 0, 0, 3, buf);
            } else {
                SMPV(sIN, OA, lsA, false, 0, 0, 3, buf);
            }
        }
        __syncthreads();
    };

    // prologue: K(tau_0) into buf 0
    STAGE_K(0, (grp == 0) ? 0 : split);
    __syncthreads();

    // rounds 0..16 (17 rounds, fixed for every block)
    for (int i = 0; i < 8; i++) {
        ROUND(2 * i, 0, stX, stY);
        ROUND(2 * i + 1, 1, stY, stX);
    }
    ROUND(16, 0, stX, stY);

    // group1 epilogue: masked softmax+PV of diag tile (scores in stY,
    // V(qa) staged in round 16 into Vbuf[1])
    if (grp == 1)
        SMPV(stY, OA, lsA, true, qa * 64, qidxA, w, 1);

    __syncthreads();   // all LDS buffer reads done before combine area reuse

    // ---- A-partial row sums (both groups)
    lsA += __shfl_xor(lsA, 16);
    lsA += __shfl_xor(lsA, 32);

    float s_acc = 0.0f, ss_acc = 0.0f;

    if (grp == 1) {
        float* po = cmbO + w * 1024 + lane * 16;
#pragma unroll
        for (int dt = 0; dt < 4; dt++)
            *(f32x4*)(po + dt * 4) = OA[dt];
        if (lane < 16) cmbLS[w * 16 + l16] = lsA;
    } else {
        // finalize B meanwhile
        lsB += __shfl_xor(lsB, 16);
        lsB += __shfl_xor(lsB, 32);
        float invB = 1.0f / lsB;
        const float* XpB = X + (bS + qidxB) * Udim + h * Dh;
        bf16_t* RpB = R + (bS + qidxB) * Udim + h * Dh;
#pragma unroll
        for (int dt = 0; dt < 4; dt++) {
            f32x4 xv = *(const f32x4*)(XpB + dt * 16 + quad * 4);
            f32x4 o = OB[dt] * invB + xv;
            bf16x4 ob;
#pragma unroll
            for (int r2 = 0; r2 < 4; r2++) {
                ob[r2] = (bf16_t)o[r2];
                s_acc += o[r2];
                ss_acc += o[r2] * o[r2];
            }
            *(bf16x4*)(RpB + dt * 16 + quad * 4) = ob;
        }
    }
    __syncthreads();

    if (grp == 0) {
        const float* po = cmbO + w * 1024 + lane * 16;
#pragma unroll
        for (int dt = 0; dt < 4; dt++)
            OA[dt] += *(const f32x4*)(po + dt * 4);
        lsA += cmbLS[w * 16 + l16];
        float invA = 1.0f / lsA;
        const float* XpA = X + (bS + qidxA) * Udim + h * Dh;
        bf16_t* RpA = R + (bS + qidxA) * Udim + h * Dh;
#pragma unroll
        for (int dt = 0; dt < 4; dt++) {
            f32x4 xv = *(const f32x4*)(XpA + dt * 16 + quad * 4);
            f32x4 o = OA[dt] * invA + xv;
            bf16x4 ob;
#pragma unroll
            for (int r2 = 0; r2 < 4; r2++) {
                ob[r2] = (bf16_t)o[r2];
                s_acc += o[r2];
                ss_acc += o[r2] * o[r2];
            }
            *(bf16x4*)(RpA + dt * 16 + quad * 4) = ob;
        }
    }

    // ---- LN stats reduction over all 8 waves
#pragma unroll
    for (int o = 1; o < 64; o <<= 1) {
        s_acc += __shfl_xor(s_acc, o);
        ss_acc += __shfl_xor(ss_acc, o);
    }
    int w8 = tid >> 6;
    if (lane == 0) { red[w8] = s_acc; red[8 + w8] = ss_acc; }
    __syncthreads();
    if (tid == 0) {
        float s = 0.0f, ss = 0.0f;
#pragma unroll
        for (int i = 0; i < 8; i++) { s += red[i]; ss += red[8 + i]; }
        atomicAdd(&stats[b], s);
        atomicAdd(&stats[2 + b], ss);
    }
}

// ---------------------------------------------------------------- LN apply
__global__ __launch_bounds__(256)
void ln_norm(const bf16_t* __restrict__ R, const float* __restrict__ gamma,
             const float* __restrict__ beta, const float* __restrict__ stats,
             float* __restrict__ out)
{
    constexpr float invN = 1.0f / (float)PerBatch;
    float mu[2], inv[2];
#pragma unroll
    for (int b = 0; b < 2; b++) {
        float m = stats[b] * invN;
        float var = stats[2 + b] * invN - m * m;
        mu[b] = m;
        inv[b] = rsqrtf(var + 1e-5f);
    }
    int i = blockIdx.x * 256 + threadIdx.x;      // over 8-elem groups, 512K
    int f = i * 8;
    int b = f >> 21;
    int su = f & (PerBatch - 1);
    bf16x8 rv = *(const bf16x8*)(R + f);
    float4 g0 = *(const float4*)(gamma + su);
    float4 g1 = *(const float4*)(gamma + su + 4);
    float4 be0 = *(const float4*)(beta + su);
    float4 be1 = *(const float4*)(beta + su + 4);
    float4 o0, o1;
    o0.x = ((float)rv[0] - mu[b]) * inv[b] * g0.x + be0.x;
    o0.y = ((float)rv[1] - mu[b]) * inv[b] * g0.y + be0.y;
    o0.z = ((float)rv[2] - mu[b]) * inv[b] * g0.z + be0.z;
    o0.w = ((float)rv[3] - mu[b]) * inv[b] * g0.w + be0.w;
    o1.x = ((float)rv[4] - mu[b]) * inv[b] * g1.x + be1.x;
    o1.y = ((float)rv[5] - mu[b]) * inv[b] * g1.y + be1.y;
    o1.z = ((float)rv[6] - mu[b]) * inv[b] * g1.z + be1.z;
    o1.w = ((float)rv[7] - mu[b]) * inv[b] * g1.w + be1.w;
    *(float4*)(out + f) = o0;
    *(float4*)(out + f + 4) = o1;
}

// ---------------------------------------------------------------- launch
extern "C" void kernel_launch(void* const* d_in, const int* in_sizes, int n_in,
                              void* d_out, int out_size, void* d_ws, size_t ws_size,
                              hipStream_t stream)
{
    const float* X     = (const float*)d_in[0];
    const float* Wq    = (const float*)d_in[1];
    const float* bq    = (const float*)d_in[2];
    const float* Wk    = (const float*)d_in[3];
    const float* bk    = (const float*)d_in[4];
    const float* Wv    = (const float*)d_in[5];
    const float* bv    = (const float*)d_in[6];
    const float* gamma = (const float*)d_in[7];
    const float* beta  = (const float*)d_in[8];
    float* out = (float*)d_out;

    char* ws = (char*)d_ws;
    size_t off = 0;
    auto alloc = [&](size_t bytes) -> void* {
        void* p = ws + off;
        off += (bytes + 255) & ~(size_t)255;
        return p;
    };
    bf16_t* Xb = (bf16_t*)alloc((size_t)Mrows * Cdim * 2);
    bf16_t* Tq = (bf16_t*)alloc((size_t)Cdim * Udim * 2);
    bf16_t* Tk = (bf16_t*)alloc((size_t)Cdim * Udim * 2);
    bf16_t* Tv = (bf16_t*)alloc((size_t)Cdim * Udim * 2);
    f16_t*  Qb = (f16_t*)alloc((size_t)Mrows * Udim * 2);
    f16_t*  Kb = (f16_t*)alloc((size_t)Mrows * Udim * 2);
    f16_t*  Vtb = (f16_t*)alloc((size_t)Mrows * Udim * 2);
    bf16_t* Rb = (bf16_t*)alloc((size_t)Mrows * Udim * 2);
    float*  stats = (float*)alloc(4 * sizeof(float));

    prep<<<dim3(16, 16, 4), 256, 0, stream>>>(X, Wq, Wk, Wv, Xb, Tq, Tk, Tv, stats);
    gemm_qkv<<<dim3(8, 32, 3), 256, 0, stream>>>(Xb, Tq, Tk, Tv, bq, bk, bv, Qb, Kb, Vtb);
    attn15<<<dim3(512), 512, 0, stream>>>(Qb, Kb, Vtb, X, Rb, stats);
    ln_norm<<<dim3(2048), 256, 0, stream>>>(Rb, gamma, beta, stats, out);
}

// Round 10
// 183.473 us; speedup vs baseline: 1.0743x; 1.0743x over previous
//
#include <hip/hip_runtime.h>
#include <hip/hip_bf16.h>

// Problem: B=2, S=2048, C=U=1024, H=16, dh=64. I/O FP32.
// 4 dispatches: prep, QKV GEMM (counted-vmcnt double-buffer pipeline),
// flash attention (8-wave blocks = two 4-wave groups, attn12 schedule +
// PV-DEFERRED pipeline: round r overlaps PV(tile r-1) [carried 8-VGPR f16
// pf] with QK+softmax(tile r); V staged one round behind K), LN apply.

typedef __bf16 bf16_t;
typedef __bf16 bf16x8 __attribute__((ext_vector_type(8)));
typedef __bf16 bf16x4 __attribute__((ext_vector_type(4)));
typedef _Float16 f16_t;
typedef _Float16 f16x2 __attribute__((ext_vector_type(2)));
typedef _Float16 f16x4 __attribute__((ext_vector_type(4)));
typedef _Float16 f16x8 __attribute__((ext_vector_type(8)));
typedef float f32x4 __attribute__((ext_vector_type(4)));

constexpr int Bsz = 2;
constexpr int Seq = 2048;
constexpr int Cdim = 1024;   // == U
constexpr int Udim = 1024;
constexpr int Hn = 16;
constexpr int Dh = 64;
constexpr int Mrows = Bsz * Seq;          // 4096
constexpr int PerBatch = Seq * Udim;      // 2^21
constexpr float SCLQ = 0.125f * 1.44269504088896340736f;  // /sqrt(dh) * log2e

#if __has_builtin(__builtin_amdgcn_exp2f)
#define EXP2F(x) __builtin_amdgcn_exp2f(x)
#else
#define EXP2F(x) exp2f(x)
#endif

#define AINL __attribute__((always_inline))
#define BARRIER() __builtin_amdgcn_s_barrier()
#define SCHEDB() __builtin_amdgcn_sched_barrier(0)
#define WAITV4() asm volatile("s_waitcnt vmcnt(4)" ::: "memory")
#define WAITV0() asm volatile("s_waitcnt vmcnt(0)" ::: "memory")

// async global->LDS, 16B per lane; LDS dest = wave-uniform base + lane*16
__device__ __forceinline__ void gload16(const void* g, void* l)
{
    __builtin_amdgcn_global_load_lds(
        (const __attribute__((address_space(1))) void*)g,
        (__attribute__((address_space(3))) void*)l, 16, 0, 0);
}

// pack two f32 -> f16x2 via v_cvt_pkrtz (returns __fp16x2; bit-identical)
__device__ __forceinline__ f16x2 pkrtz(float a, float b)
{
    return __builtin_bit_cast(f16x2, __builtin_amdgcn_cvt_pkrtz(a, b));
}

// ---------------------------------------------------------------- prep
__global__ __launch_bounds__(256)
void prep(const float* __restrict__ X,
          const float* __restrict__ Wq, const float* __restrict__ Wk,
          const float* __restrict__ Wv,
          bf16_t* __restrict__ Xb,
          bf16_t* __restrict__ Tq, bf16_t* __restrict__ Tk,
          bf16_t* __restrict__ Tv, float* __restrict__ stats)
{
    int z = blockIdx.z;
    int tid = threadIdx.x;
    if (z < 3) {
        const float* W = (z == 0) ? Wq : (z == 1) ? Wk : Wv;
        bf16_t* T = (z == 0) ? Tq : (z == 1) ? Tk : Tv;
        __shared__ bf16_t t[64][65];
        int x0 = blockIdx.x * 64, y0 = blockIdx.y * 64;
        int tx = tid & 63, ty = tid >> 6;
        for (int i = ty; i < 64; i += 4)
            t[i][tx] = (bf16_t)W[(size_t)(y0 + i) * Cdim + x0 + tx];
        __syncthreads();
        for (int i = ty; i < 64; i += 4)
            T[(size_t)(x0 + i) * Cdim + y0 + tx] = t[tx][i];
    } else {
        int bi = blockIdx.y * 16 + blockIdx.x;          // 0..255
        if (bi == 0 && tid < 4) stats[tid] = 0.0f;
        const float4* Xv = (const float4*)X;
#pragma unroll
        for (int k = 0; k < 16; k++) {
            int i = bi * 4096 + k * 256 + tid;          // 1M float4 total
            float4 v = Xv[i];
            bf16x4 o = { (bf16_t)v.x, (bf16_t)v.y, (bf16_t)v.z, (bf16_t)v.w };
            *(bf16x4*)(Xb + (size_t)i * 4) = o;
        }
    }
}

// ---------------------------------------------------------------- QKV GEMM
// 128x128 tile, BK=32, double-buffered LDS + counted vmcnt.
// z==0: Q pre-scaled by SCLQ. z==1: K. z==2: V -> Vt[b][h][d][s].
__global__ __launch_bounds__(256)
void gemm_qkv(const bf16_t* __restrict__ X,
              const bf16_t* __restrict__ Wt0, const bf16_t* __restrict__ Wt1,
              const bf16_t* __restrict__ Wt2,
              const float* __restrict__ b0, const float* __restrict__ b1,
              const float* __restrict__ b2,
              f16_t* __restrict__ O0, f16_t* __restrict__ O1, f16_t* __restrict__ O2v)
{
    int z = blockIdx.z;
    const bf16_t* Wt = (z == 0) ? Wt0 : (z == 1) ? Wt1 : Wt2;
    const float* bias = (z == 0) ? b0 : (z == 1) ? b1 : b2;
    float scl = (z == 0) ? SCLQ : 1.0f;

    constexpr int Kd = 1024, Nd = 1024;
    __shared__ __align__(16) bf16_t As[2][4096];
    __shared__ __align__(16) bf16_t Bs[2][4096];

    int tid = threadIdx.x;
    int wave = tid >> 6, lane = tid & 63, quad = lane >> 4, l16 = lane & 15;
    int wm = (wave & 1) * 64, wn = (wave >> 1) * 64;
    int m0 = blockIdx.y * 128, n0 = blockIdx.x * 128;

    f32x4 acc[4][4] = {};

    int e0 = wave * 512 + lane * 8;
    int r0 = e0 >> 5, c0 = e0 & 31;
    int e1 = e0 + 2048;
    int r1 = e1 >> 5, c1 = e1 & 31;
    const bf16_t* Ag = X + (size_t)m0 * Kd;
    const bf16_t* Bg = Wt + (size_t)n0 * Kd;

    auto STG = [&](int nb, int k0) AINL {
        gload16(Ag + (size_t)r0 * Kd + k0 + c0, &As[nb][wave * 512]);
        gload16(Ag + (size_t)r1 * Kd + k0 + c1, &As[nb][2048 + wave * 512]);
        gload16(Bg + (size_t)r0 * Kd + k0 + c0, &Bs[nb][wave * 512]);
        gload16(Bg + (size_t)r1 * Kd + k0 + c1, &Bs[nb][2048 + wave * 512]);
    };

    int kNext = 32;
    auto STEP = [&](int buf, bool doStage) AINL {
        BARRIER();                       // WAR: prev step's readers of buf^1 done
        if (doStage) { STG(buf ^ 1, kNext); kNext += 32; WAITV4(); }
        else WAITV0();
        BARRIER();                       // all waves' current-step loads landed
        SCHEDB();
        bf16x8 af[4], bfr[4];
#pragma unroll
        for (int i = 0; i < 4; i++)
            af[i] = *(const bf16x8*)&As[buf][(wm + i * 16 + l16) * 32 + quad * 8];
#pragma unroll
        for (int i = 0; i < 4; i++)
            bfr[i] = *(const bf16x8*)&Bs[buf][(wn + i * 16 + l16) * 32 + quad * 8];
#pragma unroll
        for (int mt = 0; mt < 4; mt++)
#pragma unroll
            for (int nt = 0; nt < 4; nt++)
                acc[mt][nt] = __builtin_amdgcn_mfma_f32_16x16x32_bf16(
                    af[mt], bfr[nt], acc[mt][nt], 0, 0, 0);
    };

    STG(0, 0);                           // prologue: K-step 0 into buf 0
    for (int it = 0; it < 15; it++) { STEP(0, true); STEP(1, true); }  // steps 0..29
    STEP(0, true);                       // step 30 (stages k=992)
    STEP(1, false);                      // step 31 (no successor)

    if (z < 2) {
        f16_t* Og = (z == 0) ? O0 : O1;
#pragma unroll
        for (int nt = 0; nt < 4; nt++) {
            int col = n0 + wn + nt * 16 + l16;
            float bv = bias[col];
#pragma unroll
            for (int mt = 0; mt < 4; mt++) {
                int row = m0 + wm + mt * 16 + quad * 4;
#pragma unroll
                for (int r = 0; r < 4; r++)
                    Og[(size_t)(row + r) * Nd + col] = (f16_t)((acc[mt][nt][r] + bv) * scl);
            }
        }
    } else {
        int bb = m0 >> 11;
#pragma unroll
        for (int nt = 0; nt < 4; nt++) {
            int col = n0 + wn + nt * 16 + l16;
            float bv = bias[col];
            int h = col >> 6, d = col & 63;
            f16_t* vbase = O2v + (((size_t)(bb * Hn + h) * Dh + d) << 11);
#pragma unroll
            for (int mt = 0; mt < 4; mt++) {
                int row = m0 + wm + mt * 16 + quad * 4;
                int s = row & (Seq - 1);
                f16x4 pk;
#pragma unroll
                for (int r = 0; r < 4; r++) pk[r] = (f16_t)(acc[mt][nt][r] + bv);
                *(f16x4*)(vbase + s) = pk;
            }
        }
    }
}

// ---------------------------------------------------------------- attention
// 512 blocks x 512 threads (two 4-wave groups). attn12 schedule + PV-
// deferred pipeline. Group0 stream: B tiles 0..qb (masked diag at r==qb)
// then A tiles 0..split-1 (split=15-pi), 16 QK rounds. Group1 stream: A
// tiles split..qa (masked diag at r==16), 17 QK rounds. All blocks run 17
// barrier-rounds. Round r: {stage K(tau_{r+1})->Kbuf[buf^1] & V(tau_r)->
// Vbuf[buf]; QK(tau_r)->sc; PV(tau_{r-1}) from CARRIED pfC (8 VGPR) with
// V in Vbuf[buf^1]; softmax(sc)->pfC; __syncthreads}. PV is independent
// of QK/softmax -> intra-wave MFMA/trans overlap. Group1 epilogue PV of
// tau_16 from Vbuf[0] before combine-area reuse. Intra-block LDS combine.
__global__ __launch_bounds__(512, 4)
void attn16(const f16_t* __restrict__ Q, const f16_t* __restrict__ K,
            const f16_t* __restrict__ Vt, const float* __restrict__ X,
            bf16_t* __restrict__ R, float* __restrict__ stats)
{
    int id = blockIdx.x;
    int c = id & 7;            // XCD slot (4 bh per XCD -> K/V L2-resident)
    int rr = id >> 3;          // 0..63
    int g = rr & 3;
    int pi = rr >> 2;          // 0..15
    int bh = (g << 3) | c;
    int b = bh >> 4, h = bh & 15;
    int qa = 31 - pi, qb = pi, split = 15 - pi;

    int tid = threadIdx.x;
    int grp = tid >> 8;              // 0 / 1
    int w = (tid >> 6) & 3;          // wave within group
    int lane = tid & 63, quad = lane >> 4, l16 = lane & 15;
    size_t bS = (size_t)b * Seq;

    __shared__ __align__(16) char ldsRaw[65600];
    f16_t* KsBase = (f16_t*)(ldsRaw + grp * 32768);
    f16_t* VsBase = (f16_t*)(ldsRaw + grp * 32768 + 16384);
    float* cmbO   = (float*)(ldsRaw + 32768);   // 16KB (aliases grp1 K bufs, dead)
    float* cmbLS  = (float*)(ldsRaw + 49152);   // 256B (aliases grp1 V buf0, dead)
    float* red    = (float*)(ldsRaw + 65536);   // 16 f32

    const f16_t* Kg = K + bS * Udim + h * Dh;
    const f16_t* Vg = Vt + ((size_t)(b * Hn + h)) * Dh * Seq;

    // staging geometry (pre-swizzled global source, rule #21)
    int srow = w * 8 + (lane >> 3);
    int schunk = (lane & 7) ^ ((lane >> 3) & 7);

    int qidxA = qa * 64 + w * 16 + l16;
    int qidxB = qb * 64 + w * 16 + l16;
    const f16_t* QpA = Q + (bS + qidxA) * Udim + h * Dh;
    const f16_t* QpB = Q + (bS + qidxB) * Udim + h * Dh;
    f16x8 qfA[2], qfB[2];
#pragma unroll
    for (int s2 = 0; s2 < 2; s2++) {
        qfA[s2] = *(const f16x8*)(QpA + s2 * 32 + quad * 8);
        qfB[s2] = *(const f16x8*)(QpB + s2 * 32 + quad * 8);
    }

    // lane-constant swizzled read offsets (f16 elements)
    int m = l16 & 7;
    int kO0 = l16 * 64 + ((quad ^ m) << 3);
    int kO1 = l16 * 64 + (((4 + quad) ^ m) << 3);
    int vO[4];
#pragma unroll
    for (int t = 0; t < 4; t++)
        vO[t] = l16 * 64 + (((t * 32 + quad * 8) ^ (m << 4)) >> 1);

    f32x4 OA[4] = {}, OB[4] = {};
    float lsA = 0.0f, lsB = 0.0f;
    f16x4 pfC[4] = {};               // carried packed probabilities (8 VGPR)

    // group0 tile stream: rounds 0..15 -> B 0..qb then A 0..split-1
    auto tl0 = [&](int rho) AINL -> int { return (rho <= qb) ? rho : rho - qb - 1; };

    auto STAGE_K = [&](int nb, int tl) AINL {
        const f16_t* kp = Kg + (size_t)(tl * 64 + srow) * Udim + schunk * 8;
        f16_t* kd = KsBase + nb * 4096;
        gload16(kp, kd + w * 512);
        gload16(kp + (size_t)32 * Udim, kd + 2048 + w * 512);
    };
    auto STAGE_V = [&](int nb, int tl) AINL {
        const f16_t* vp = Vg + (size_t)srow * Seq + tl * 64 + schunk * 8;
        f16_t* vd = VsBase + nb * 4096;
        gload16(vp, vd + w * 512);
        gload16(vp + (size_t)32 * Seq, vd + 2048 + w * 512);
    };

    // QK of tile in Kbuf[buf] into sc (sub-tiles t<=tcap)
    auto QK = [&](int buf, const f16x8 (&qf)[2], f32x4 (&sc)[4], int tcap) AINL {
        const f16_t* Kb = KsBase + buf * 4096;
#pragma unroll
        for (int t = 0; t < 4; t++) {
            if (t <= tcap) {
                f16x8 kf0 = *(const f16x8*)&Kb[kO0 + t * 1024];
                f16x8 kf1 = *(const f16x8*)&Kb[kO1 + t * 1024];
                f32x4 a = {};
                a = __builtin_amdgcn_mfma_f32_16x16x32_f16(kf0, qf[0], a, 0, 0, 0);
                a = __builtin_amdgcn_mfma_f32_16x16x32_f16(kf1, qf[1], a, 0, 0, 0);
                sc[t] = a;
            }
        }
    };

    // PV of carried pfC; V in Vbuf[vb]; sub-tiles t<=ptc
    auto PV = [&](int vb, f32x4 (&O)[4], int ptc) AINL {
        const f16_t* Vb = VsBase + vb * 4096;
#pragma unroll
        for (int t = 0; t < 4; t++) {
            if (t <= ptc) {
#pragma unroll
                for (int dt = 0; dt < 4; dt++) {
                    f16x4 vf = *(const f16x4*)&Vb[vO[t] + dt * 1024];
                    O[dt] = __builtin_amdgcn_mfma_f32_16x16x16f16(vf, pfC[t], O[dt], 0, 0, 0);
                }
            }
        }
    };

    // softmax of sc -> pfC (sub-tiles t<=tcap), accumulate ls
    auto SM = [&](f32x4 (&sc)[4], float& ls, bool msk, int kv0, int qidx, int tcap) AINL {
#pragma unroll
        for (int t = 0; t < 4; t++) {
            if (t <= tcap) {
                float pv[4];
#pragma unroll
                for (int r2 = 0; r2 < 4; r2++) {
                    float sv = sc[t][r2];
                    if (msk && (kv0 + t * 16 + quad * 4 + r2 > qidx)) sv = -1e30f;
                    pv[r2] = EXP2F(sv);
                    ls += pv[r2];
                }
                f16x2 lo = pkrtz(pv[0], pv[1]);
                f16x2 hi = pkrtz(pv[2], pv[3]);
                pfC[t][0] = lo[0]; pfC[t][1] = lo[1];
                pfC[t][2] = hi[0]; pfC[t][3] = hi[1];
            }
        }
    };

    int r = 0;
    auto ROUND = [&](int buf) AINL {
        // ---- staging: K one tile ahead; V current tile (consumed next round)
        if (grp == 0) {
            if (r <= 14) STAGE_K(buf ^ 1, tl0(r + 1));
            if (r <= 15) STAGE_V(buf, tl0(r));
        } else {
            if (r <= 15) STAGE_K(buf ^ 1, split + r + 1);
            STAGE_V(buf, split + r);
        }
        // ---- QK(tau_r) -> sc (local)
        f32x4 sc[4];
        bool doQK = (grp == 1) || (r <= 15);
        if (doQK) {
            if (grp == 0) {
                if (r <= qb) QK(buf, qfB, sc, (r == qb) ? w : 3);
                else         QK(buf, qfA, sc, 3);
            } else {
                QK(buf, qfA, sc, (r == 16) ? w : 3);
            }
        }
        // ---- PV(tau_{r-1}) from carried pfC; V in Vbuf[buf^1].
        //      Independent of QK/softmax -> overlaps. Must precede SM (WAR).
        if (r >= 1) {
            if (grp == 0) {
                if (r - 1 <= qb) PV(buf ^ 1, OB, (r - 1 == qb) ? w : 3);
                else             PV(buf ^ 1, OA, 3);
            } else {
                PV(buf ^ 1, OA, 3);
            }
        }
        // ---- softmax(sc) -> pfC (overwrites carry AFTER PV consumed it)
        if (doQK) {
            if (grp == 0) {
                if (r < qb)       SM(sc, lsB, false, 0, 0, 3);
                else if (r == qb) SM(sc, lsB, true, qb * 64, qidxB, w);
                else              SM(sc, lsA, false, 0, 0, 3);
            } else {
                if (r == 16) SM(sc, lsA, true, qa * 64, qidxA, w);
                else         SM(sc, lsA, false, 0, 0, 3);
            }
        }
        __syncthreads();
        r++;
    };

    // prologue: K(tau_0) into Kbuf[0]
    STAGE_K(0, (grp == 0) ? 0 : split);
    __syncthreads();

    // rounds 0..16 (17 barrier-rounds for every block)
    for (int i = 0; i < 8; i++) { ROUND(0); ROUND(1); }
    ROUND(0);   // round 16 (buf=0): V(tau_16)->Vbuf[0]; grp1 masked QK; PV(tau_15)

    // group1 epilogue: PV of tau_16 (diag) from Vbuf[0] — before combine reuse
    if (grp == 1)
        PV(0, OA, w);

    __syncthreads();   // all LDS buffer reads done before combine area reuse

    // ---- A-partial row sums (both groups)
    lsA += __shfl_xor(lsA, 16);
    lsA += __shfl_xor(lsA, 32);

    float s_acc = 0.0f, ss_acc = 0.0f;

    if (grp == 1) {
        float* po = cmbO + w * 1024 + lane * 16;
#pragma unroll
        for (int dt = 0; dt < 4; dt++)
            *(f32x4*)(po + dt * 4) = OA[dt];
        if (lane < 16) cmbLS[w * 16 + l16] = lsA;
    } else {
        // finalize B meanwhile
        lsB += __shfl_xor(lsB, 16);
        lsB += __shfl_xor(lsB, 32);
        float invB = 1.0f / lsB;
        const float* XpB = X + (bS + qidxB) * Udim + h * Dh;
        bf16_t* RpB = R + (bS + qidxB) * Udim + h * Dh;
#pragma unroll
        for (int dt = 0; dt < 4; dt++) {
            f32x4 xv = *(const f32x4*)(XpB + dt * 16 + quad * 4);
            f32x4 o = OB[dt] * invB + xv;
            bf16x4 ob;
#pragma unroll
            for (int r2 = 0; r2 < 4; r2++) {
                ob[r2] = (bf16_t)o[r2];
                s_acc += o[r2];
                ss_acc += o[r2] * o[r2];
            }
            *(bf16x4*)(RpB + dt * 16 + quad * 4) = ob;
        }
    }
    __syncthreads();

    if (grp == 0) {
        const float* po = cmbO + w * 1024 + lane * 16;
#pragma unroll
        for (int dt = 0; dt < 4; dt++)
            OA[dt] += *(const f32x4*)(po + dt * 4);
        lsA += cmbLS[w * 16 + l16];
        float invA = 1.0f / lsA;
        const float* XpA = X + (bS + qidxA) * Udim + h * Dh;
        bf16_t* RpA = R + (bS + qidxA) * Udim + h * Dh;
#pragma unroll
        for (int dt = 0; dt < 4; dt++) {
            f32x4 xv = *(const f32x4*)(XpA + dt * 16 + quad * 4);
            f32x4 o = OA[dt] * invA + xv;
            bf16x4 ob;
#pragma unroll
            for (int r2 = 0; r2 < 4; r2++) {
                ob[r2] = (bf16_t)o[r2];
                s_acc += o[r2];
                ss_acc += o[r2] * o[r2];
            }
            *(bf16x4*)(RpA + dt * 16 + quad * 4) = ob;
        }
    }

    // ---- LN stats reduction over all 8 waves
#pragma unroll
    for (int o = 1; o < 64; o <<= 1) {
        s_acc += __shfl_xor(s_acc, o);
        ss_acc += __shfl_xor(ss_acc, o);
    }
    int w8 = tid >> 6;
    if (lane == 0) { red[w8] = s_acc; red[8 + w8] = ss_acc; }
    __syncthreads();
    if (tid == 0) {
        float s = 0.0f, ss = 0.0f;
#pragma unroll
        for (int i = 0; i < 8; i++) { s += red[i]; ss += red[8 + i]; }
        atomicAdd(&stats[b], s);
        atomicAdd(&stats[2 + b], ss);
    }
}

// ---------------------------------------------------------------- LN apply
__global__ __launch_bounds__(256)
void ln_norm(const bf16_t* __restrict__ R, const float* __restrict__ gamma,
             const float* __restrict__ beta, const float* __restrict__ stats,
             float* __restrict__ out)
{
    constexpr float invN = 1.0f / (float)PerBatch;
    float mu[2], inv[2];
#pragma unroll
    for (int b = 0; b < 2; b++) {
        float m = stats[b] * invN;
        float var = stats[2 + b] * invN - m * m;
        mu[b] = m;
        inv[b] = rsqrtf(var + 1e-5f);
    }
    int i = blockIdx.x * 256 + threadIdx.x;      // over 8-elem groups, 512K
    int f = i * 8;
    int b = f >> 21;
    int su = f & (PerBatch - 1);
    bf16x8 rv = *(const bf16x8*)(R + f);
    float4 g0 = *(const float4*)(gamma + su);
    float4 g1 = *(const float4*)(gamma + su + 4);
    float4 be0 = *(const float4*)(beta + su);
    float4 be1 = *(const float4*)(beta + su + 4);
    float4 o0, o1;
    o0.x = ((float)rv[0] - mu[b]) * inv[b] * g0.x + be0.x;
    o0.y = ((float)rv[1] - mu[b]) * inv[b] * g0.y + be0.y;
    o0.z = ((float)rv[2] - mu[b]) * inv[b] * g0.z + be0.z;
    o0.w = ((float)rv[3] - mu[b]) * inv[b] * g0.w + be0.w;
    o1.x = ((float)rv[4] - mu[b]) * inv[b] * g1.x + be1.x;
    o1.y = ((float)rv[5] - mu[b]) * inv[b] * g1.y + be1.y;
    o1.z = ((float)rv[6] - mu[b]) * inv[b] * g1.z + be1.z;
    o1.w = ((float)rv[7] - mu[b]) * inv[b] * g1.w + be1.w;
    *(float4*)(out + f) = o0;
    *(float4*)(out + f + 4) = o1;
}

// ---------------------------------------------------------------- launch
extern "C" void kernel_launch(void* const* d_in, const int* in_sizes, int n_in,
                              void* d_out, int out_size, void* d_ws, size_t ws_size,
                              hipStream_t stream)
{
    const float* X     = (const float*)d_in[0];
    const float* Wq    = (const float*)d_in[1];
    const float* bq    = (const float*)d_in[2];
    const float* Wk    = (const float*)d_in[3];
    const float* bk    = (const float*)d_in[4];
    const float* Wv    = (const float*)d_in[5];
    const float* bv    = (const float*)d_in[6];
    const float* gamma = (const float*)d_in[7];
    const float* beta  = (const float*)d_in[8];
    float* out = (float*)d_out;

    char* ws = (char*)d_ws;
    size_t off = 0;
    auto alloc = [&](size_t bytes) -> void* {
        void* p = ws + off;
        off += (bytes + 255) & ~(size_t)255;
        return p;
    };
    bf16_t* Xb = (bf16_t*)alloc((size_t)Mrows * Cdim * 2);
    bf16_t* Tq = (bf16_t*)alloc((size_t)Cdim * Udim * 2);
    bf16_t* Tk = (bf16_t*)alloc((size_t)Cdim * Udim * 2);
    bf16_t* Tv = (bf16_t*)alloc((size_t)Cdim * Udim * 2);
    f16_t*  Qb = (f16_t*)alloc((size_t)Mrows * Udim * 2);
    f16_t*  Kb = (f16_t*)alloc((size_t)Mrows * Udim * 2);
    f16_t*  Vtb = (f16_t*)alloc((size_t)Mrows * Udim * 2);
    bf16_t* Rb = (bf16_t*)alloc((size_t)Mrows * Udim * 2);
    float*  stats = (float*)alloc(4 * sizeof(float));

    prep<<<dim3(16, 16, 4), 256, 0, stream>>>(X, Wq, Wk, Wv, Xb, Tq, Tk, Tv, stats);
    gemm_qkv<<<dim3(8, 32, 3), 256, 0, stream>>>(Xb, Tq, Tk, Tv, bq, bk, bv, Qb, Kb, Vtb);
    attn16<<<dim3(512), 512, 0, stream>>>(Qb, Kb, Vtb, X, Rb, stats);
    ln_norm<<<dim3(2048), 256, 0, stream>>>(Rb, gamma, beta, stats, out);
}

// Round 11
// 182.415 us; speedup vs baseline: 1.0806x; 1.0058x over previous
//
#include <hip/hip_runtime.h>
#include <hip/hip_bf16.h>

// Problem: B=2, S=2048, C=U=1024, H=16, dh=64. I/O FP32.
// 4 dispatches: prep, QKV GEMM (counted-vmcnt double-buffer pipeline),
// flash attention (8-wave blocks = two 4-wave groups with independent kv
// streams; pair (qa,qb) kv-split at split=15-pi; intra-block additive
// combine through LDS; plain __syncthreads rounds [best-measured attn12
// schedule]; + s_setprio(1) around MFMA clusters [T5, m191 regime]),
// LN apply.

typedef __bf16 bf16_t;
typedef __bf16 bf16x8 __attribute__((ext_vector_type(8)));
typedef __bf16 bf16x4 __attribute__((ext_vector_type(4)));
typedef _Float16 f16_t;
typedef _Float16 f16x2 __attribute__((ext_vector_type(2)));
typedef _Float16 f16x4 __attribute__((ext_vector_type(4)));
typedef _Float16 f16x8 __attribute__((ext_vector_type(8)));
typedef float f32x4 __attribute__((ext_vector_type(4)));

constexpr int Bsz = 2;
constexpr int Seq = 2048;
constexpr int Cdim = 1024;   // == U
constexpr int Udim = 1024;
constexpr int Hn = 16;
constexpr int Dh = 64;
constexpr int Mrows = Bsz * Seq;          // 4096
constexpr int PerBatch = Seq * Udim;      // 2^21
constexpr float SCLQ = 0.125f * 1.44269504088896340736f;  // /sqrt(dh) * log2e

#if __has_builtin(__builtin_amdgcn_exp2f)
#define EXP2F(x) __builtin_amdgcn_exp2f(x)
#else
#define EXP2F(x) exp2f(x)
#endif

#define AINL __attribute__((always_inline))
#define BARRIER() __builtin_amdgcn_s_barrier()
#define SCHEDB() __builtin_amdgcn_sched_barrier(0)
#define SETP(x) __builtin_amdgcn_s_setprio(x)
#define WAITV4() asm volatile("s_waitcnt vmcnt(4)" ::: "memory")
#define WAITV0() asm volatile("s_waitcnt vmcnt(0)" ::: "memory")

// async global->LDS, 16B per lane; LDS dest = wave-uniform base + lane*16
__device__ __forceinline__ void gload16(const void* g, void* l)
{
    __builtin_amdgcn_global_load_lds(
        (const __attribute__((address_space(1))) void*)g,
        (__attribute__((address_space(3))) void*)l, 16, 0, 0);
}

// pack two f32 -> f16x2 via v_cvt_pkrtz (returns __fp16x2; bit-identical)
__device__ __forceinline__ f16x2 pkrtz(float a, float b)
{
    return __builtin_bit_cast(f16x2, __builtin_amdgcn_cvt_pkrtz(a, b));
}

// ---------------------------------------------------------------- prep
__global__ __launch_bounds__(256)
void prep(const float* __restrict__ X,
          const float* __restrict__ Wq, const float* __restrict__ Wk,
          const float* __restrict__ Wv,
          bf16_t* __restrict__ Xb,
          bf16_t* __restrict__ Tq, bf16_t* __restrict__ Tk,
          bf16_t* __restrict__ Tv, float* __restrict__ stats)
{
    int z = blockIdx.z;
    int tid = threadIdx.x;
    if (z < 3) {
        const float* W = (z == 0) ? Wq : (z == 1) ? Wk : Wv;
        bf16_t* T = (z == 0) ? Tq : (z == 1) ? Tk : Tv;
        __shared__ bf16_t t[64][65];
        int x0 = blockIdx.x * 64, y0 = blockIdx.y * 64;
        int tx = tid & 63, ty = tid >> 6;
        for (int i = ty; i < 64; i += 4)
            t[i][tx] = (bf16_t)W[(size_t)(y0 + i) * Cdim + x0 + tx];
        __syncthreads();
        for (int i = ty; i < 64; i += 4)
            T[(size_t)(x0 + i) * Cdim + y0 + tx] = t[tx][i];
    } else {
        int bi = blockIdx.y * 16 + blockIdx.x;          // 0..255
        if (bi == 0 && tid < 4) stats[tid] = 0.0f;
        const float4* Xv = (const float4*)X;
#pragma unroll
        for (int k = 0; k < 16; k++) {
            int i = bi * 4096 + k * 256 + tid;          // 1M float4 total
            float4 v = Xv[i];
            bf16x4 o = { (bf16_t)v.x, (bf16_t)v.y, (bf16_t)v.z, (bf16_t)v.w };
            *(bf16x4*)(Xb + (size_t)i * 4) = o;
        }
    }
}

// ---------------------------------------------------------------- QKV GEMM
// 128x128 tile, BK=32, double-buffered LDS + counted vmcnt (measured ~3us
// better than syncthreads variant, R5->R6 A/B).
// z==0: Q pre-scaled by SCLQ. z==1: K. z==2: V -> Vt[b][h][d][s].
__global__ __launch_bounds__(256)
void gemm_qkv(const bf16_t* __restrict__ X,
              const bf16_t* __restrict__ Wt0, const bf16_t* __restrict__ Wt1,
              const bf16_t* __restrict__ Wt2,
              const float* __restrict__ b0, const float* __restrict__ b1,
              const float* __restrict__ b2,
              f16_t* __restrict__ O0, f16_t* __restrict__ O1, f16_t* __restrict__ O2v)
{
    int z = blockIdx.z;
    const bf16_t* Wt = (z == 0) ? Wt0 : (z == 1) ? Wt1 : Wt2;
    const float* bias = (z == 0) ? b0 : (z == 1) ? b1 : b2;
    float scl = (z == 0) ? SCLQ : 1.0f;

    constexpr int Kd = 1024, Nd = 1024;
    __shared__ __align__(16) bf16_t As[2][4096];
    __shared__ __align__(16) bf16_t Bs[2][4096];

    int tid = threadIdx.x;
    int wave = tid >> 6, lane = tid & 63, quad = lane >> 4, l16 = lane & 15;
    int wm = (wave & 1) * 64, wn = (wave >> 1) * 64;
    int m0 = blockIdx.y * 128, n0 = blockIdx.x * 128;

    f32x4 acc[4][4] = {};

    int e0 = wave * 512 + lane * 8;
    int r0 = e0 >> 5, c0 = e0 & 31;
    int e1 = e0 + 2048;
    int r1 = e1 >> 5, c1 = e1 & 31;
    const bf16_t* Ag = X + (size_t)m0 * Kd;
    const bf16_t* Bg = Wt + (size_t)n0 * Kd;

    auto STG = [&](int nb, int k0) AINL {
        gload16(Ag + (size_t)r0 * Kd + k0 + c0, &As[nb][wave * 512]);
        gload16(Ag + (size_t)r1 * Kd + k0 + c1, &As[nb][2048 + wave * 512]);
        gload16(Bg + (size_t)r0 * Kd + k0 + c0, &Bs[nb][wave * 512]);
        gload16(Bg + (size_t)r1 * Kd + k0 + c1, &Bs[nb][2048 + wave * 512]);
    };

    int kNext = 32;
    auto STEP = [&](int buf, bool doStage) AINL {
        BARRIER();                       // WAR: prev step's readers of buf^1 done
        if (doStage) { STG(buf ^ 1, kNext); kNext += 32; WAITV4(); }
        else WAITV0();
        BARRIER();                       // all waves' current-step loads landed
        SCHEDB();
        bf16x8 af[4], bfr[4];
#pragma unroll
        for (int i = 0; i < 4; i++)
            af[i] = *(const bf16x8*)&As[buf][(wm + i * 16 + l16) * 32 + quad * 8];
#pragma unroll
        for (int i = 0; i < 4; i++)
            bfr[i] = *(const bf16x8*)&Bs[buf][(wn + i * 16 + l16) * 32 + quad * 8];
#pragma unroll
        for (int mt = 0; mt < 4; mt++)
#pragma unroll
            for (int nt = 0; nt < 4; nt++)
                acc[mt][nt] = __builtin_amdgcn_mfma_f32_16x16x32_bf16(
                    af[mt], bfr[nt], acc[mt][nt], 0, 0, 0);
    };

    STG(0, 0);                           // prologue: K-step 0 into buf 0
    for (int it = 0; it < 15; it++) { STEP(0, true); STEP(1, true); }  // steps 0..29
    STEP(0, true);                       // step 30 (stages k=992)
    STEP(1, false);                      // step 31 (no successor)

    if (z < 2) {
        f16_t* Og = (z == 0) ? O0 : O1;
#pragma unroll
        for (int nt = 0; nt < 4; nt++) {
            int col = n0 + wn + nt * 16 + l16;
            float bv = bias[col];
#pragma unroll
            for (int mt = 0; mt < 4; mt++) {
                int row = m0 + wm + mt * 16 + quad * 4;
#pragma unroll
                for (int r = 0; r < 4; r++)
                    Og[(size_t)(row + r) * Nd + col] = (f16_t)((acc[mt][nt][r] + bv) * scl);
            }
        }
    } else {
        int bb = m0 >> 11;
#pragma unroll
        for (int nt = 0; nt < 4; nt++) {
            int col = n0 + wn + nt * 16 + l16;
            float bv = bias[col];
            int h = col >> 6, d = col & 63;
            f16_t* vbase = O2v + (((size_t)(bb * Hn + h) * Dh + d) << 11);
#pragma unroll
            for (int mt = 0; mt < 4; mt++) {
                int row = m0 + wm + mt * 16 + quad * 4;
                int s = row & (Seq - 1);
                f16x4 pk;
#pragma unroll
                for (int r = 0; r < 4; r++) pk[r] = (f16_t)(acc[mt][nt][r] + bv);
                *(f16x4*)(vbase + s) = pk;
            }
        }
    }
}

// ---------------------------------------------------------------- attention
// attn12 schedule (best-measured 44.3us) + T5 setprio around MFMA clusters.
// 512 blocks x 512 threads (8 waves = two 4-wave groups). Block owns pair
// (qa=31-pi, qb=pi); split=15-pi. Group0: B tiles 0..qb then A tiles
// 0..split-1 (16 units). Group1: A tiles split..qa incl diag (17 units).
// Each group: own K/V double-buffer (XOR-swizzled LDS via pre-swizzled
// global_load_lds source), {stage-next, compute, __syncthreads} rounds.
// Both groups run exactly 17 rounds -> uniform duration, 16 waves/CU flat.
// A-partials (offset-free softmax => additive) combine intra-block through
// group1's dead LDS region: one __syncthreads, no fences. setprio(1) wraps
// the QK and PV MFMA clusters: with 2 independent blocks/CU, MFMA-entering
// waves preempt the other block's staging waves (m191 attn regime).
__global__ __launch_bounds__(512, 4)
void attn17(const f16_t* __restrict__ Q, const f16_t* __restrict__ K,
            const f16_t* __restrict__ Vt, const float* __restrict__ X,
            bf16_t* __restrict__ R, float* __restrict__ stats)
{
    int id = blockIdx.x;
    int c = id & 7;            // XCD slot (4 bh per XCD -> K/V L2-resident)
    int rr = id >> 3;          // 0..63
    int g = rr & 3;
    int pi = rr >> 2;          // 0..15
    int bh = (g << 3) | c;
    int b = bh >> 4, h = bh & 15;
    int qa = 31 - pi, qb = pi, split = 15 - pi;

    int tid = threadIdx.x;
    int grp = tid >> 8;              // 0 / 1
    int w = (tid >> 6) & 3;          // wave within group
    int lane = tid & 63, quad = lane >> 4, l16 = lane & 15;
    size_t bS = (size_t)b * Seq;

    // LDS: per group 32KB (K buf0|K buf1|V buf0|V buf1, 8KB each);
    // combine area aliases group1's region (dead after its loop); red at end.
    __shared__ __align__(16) char ldsRaw[65600];
    f16_t* KsBase = (f16_t*)(ldsRaw + grp * 32768);
    f16_t* VsBase = (f16_t*)(ldsRaw + grp * 32768 + 16384);
    float* cmbO   = (float*)(ldsRaw + 32768);   // 16KB: 4 waves x 64 lanes x 16 f32
    float* cmbLS  = (float*)(ldsRaw + 49152);   // 256B: 64 rows
    float* red    = (float*)(ldsRaw + 65536);   // 16 f32

    const f16_t* Kg = K + bS * Udim + h * Dh;
    const f16_t* Vg = Vt + ((size_t)(b * Hn + h)) * Dh * Seq;

    // staging geometry (pre-swizzled global source, rule #21)
    int srow = w * 8 + (lane >> 3);
    int schunk = (lane & 7) ^ ((lane >> 3) & 7);

    int qidxA = qa * 64 + w * 16 + l16;
    int qidxB = qb * 64 + w * 16 + l16;
    const f16_t* QpA = Q + (bS + qidxA) * Udim + h * Dh;
    const f16_t* QpB = Q + (bS + qidxB) * Udim + h * Dh;
    f16x8 qfA[2], qfB[2];
#pragma unroll
    for (int s2 = 0; s2 < 2; s2++) {
        qfA[s2] = *(const f16x8*)(QpA + s2 * 32 + quad * 8);
        qfB[s2] = *(const f16x8*)(QpB + s2 * 32 + quad * 8);
    }

    // lane-constant swizzled read offsets (f16 elements)
    int m = l16 & 7;
    int kO0 = l16 * 64 + ((quad ^ m) << 3);
    int kO1 = l16 * 64 + (((4 + quad) ^ m) << 3);
    int vO[4];
#pragma unroll
    for (int t = 0; t < 4; t++)
        vO[t] = l16 * 64 + (((t * 32 + quad * 8) ^ (m << 4)) >> 1);

    f32x4 OA[4] = {}, OB[4] = {};
    float lsA = 0.0f, lsB = 0.0f;

    // stage kv tile `tl` into buf nb of this group's region (4 loads)
    auto STAGE = [&](int nb, int tl) AINL {
        const f16_t* kp = Kg + (size_t)(tl * 64 + srow) * Udim + schunk * 8;
        const f16_t* vp = Vg + (size_t)srow * Seq + tl * 64 + schunk * 8;
        f16_t* kd = KsBase + nb * 4096;
        f16_t* vd = VsBase + nb * 4096;
        gload16(kp, kd + w * 512);
        gload16(kp + (size_t)32 * Udim, kd + 2048 + w * 512);
        gload16(vp, vd + w * 512);
        gload16(vp + (size_t)32 * Seq, vd + 2048 + w * 512);
    };

    // unmasked 16-row x 64-kv compute
    auto CN = [&](int buf, const f16x8 (&qf)[2], f32x4 (&O)[4], float& ls) AINL {
        const f16_t* Kb = KsBase + buf * 4096;
        const f16_t* Vb = VsBase + buf * 4096;
        f32x4 st[4];
        SETP(1);
#pragma unroll
        for (int t = 0; t < 4; t++) {
            f16x8 kf0 = *(const f16x8*)&Kb[kO0 + t * 1024];
            f16x8 kf1 = *(const f16x8*)&Kb[kO1 + t * 1024];
            f32x4 a = {};
            a = __builtin_amdgcn_mfma_f32_16x16x32_f16(kf0, qf[0], a, 0, 0, 0);
            a = __builtin_amdgcn_mfma_f32_16x16x32_f16(kf1, qf[1], a, 0, 0, 0);
            st[t] = a;
        }
        SETP(0);
        f16x4 pf[4];
#pragma unroll
        for (int t = 0; t < 4; t++) {
            float p0 = EXP2F(st[t][0]);
            float p1 = EXP2F(st[t][1]);
            float p2 = EXP2F(st[t][2]);
            float p3 = EXP2F(st[t][3]);
            ls += (p0 + p1) + (p2 + p3);
            f16x2 lo = pkrtz(p0, p1);
            f16x2 hi = pkrtz(p2, p3);
            pf[t][0] = lo[0]; pf[t][1] = lo[1];
            pf[t][2] = hi[0]; pf[t][3] = hi[1];
        }
        SETP(1);
#pragma unroll
        for (int t = 0; t < 4; t++)
#pragma unroll
            for (int dt = 0; dt < 4; dt++) {
                f16x4 vf = *(const f16x4*)&Vb[vO[t] + dt * 1024];
                O[dt] = __builtin_amdgcn_mfma_f32_16x16x16f16(vf, pf[t], O[dt], 0, 0, 0);
            }
        SETP(0);
    };

    // masked diagonal compute (sub-t <= w, wave-uniform)
    auto CM = [&](int buf, const f16x8 (&qf)[2], f32x4 (&O)[4], float& ls,
                  int kv0, int qidx) AINL {
        const f16_t* Kb = KsBase + buf * 4096;
        const f16_t* Vb = VsBase + buf * 4096;
#pragma unroll
        for (int t = 0; t < 4; t++) {
            if (t <= w) {
                f16x8 kf0 = *(const f16x8*)&Kb[kO0 + t * 1024];
                f16x8 kf1 = *(const f16x8*)&Kb[kO1 + t * 1024];
                f32x4 a = {};
                a = __builtin_amdgcn_mfma_f32_16x16x32_f16(kf0, qf[0], a, 0, 0, 0);
                a = __builtin_amdgcn_mfma_f32_16x16x32_f16(kf1, qf[1], a, 0, 0, 0);
                f16x4 pfd;
#pragma unroll
                for (int r2 = 0; r2 < 4; r2++) {
                    float sv = a[r2];
                    if (kv0 + t * 16 + quad * 4 + r2 > qidx) sv = -1e30f;  // causal
                    float pv = EXP2F(sv);
                    ls += pv;
                    pfd[r2] = (f16_t)pv;
                }
#pragma unroll
                for (int dt = 0; dt < 4; dt++) {
                    f16x4 vf = *(const f16x4*)&Vb[vO[t] + dt * 1024];
                    O[dt] = __builtin_amdgcn_mfma_f32_16x16x16f16(vf, pfd, O[dt], 0, 0, 0);
                }
            }
        }
    };

    // preload round-0 tile into buf 0
    STAGE(0, (grp == 0) ? 0 : split);
    __syncthreads();

    int r = 0;
    auto ROUND = [&](int buf) AINL {
        if (r < 16) {   // stage next round's tile (round 16 has no successor)
            int rn = r + 1;
            int tl = (grp == 0) ? ((rn <= qb) ? rn : rn - qb - 1) : (split + rn);
            STAGE(buf ^ 1, tl);
        }
        if (grp == 0) {
            if (r < qb)       CN(buf, qfB, OB, lsB);
            else if (r == qb) CM(buf, qfB, OB, lsB, qb * 64, qidxB);
            else if (r < 16)  CN(buf, qfA, OA, lsA);
            // r == 16: idle round (barrier only)
        } else {
            if (r < 16)       CN(buf, qfA, OA, lsA);
            else              CM(buf, qfA, OA, lsA, qa * 64, qidxA);
        }
        __syncthreads();
        r++;
    };

    for (int i = 0; i < 8; i++) { ROUND(0); ROUND(1); }
    ROUND(0);   // round 16

    // ---- A-partial row sums (both groups)
    lsA += __shfl_xor(lsA, 16);
    lsA += __shfl_xor(lsA, 32);

    float s_acc = 0.0f, ss_acc = 0.0f;

    if (grp == 1) {
        // publish A partials into own (dead) LDS region
        float* po = cmbO + w * 1024 + lane * 16;
#pragma unroll
        for (int dt = 0; dt < 4; dt++)
            *(f32x4*)(po + dt * 4) = OA[dt];
        if (lane < 16) cmbLS[w * 16 + l16] = lsA;
    } else {
        // finalize B meanwhile
        lsB += __shfl_xor(lsB, 16);
        lsB += __shfl_xor(lsB, 32);
        float invB = 1.0f / lsB;
        const float* XpB = X + (bS + qidxB) * Udim + h * Dh;
        bf16_t* RpB = R + (bS + qidxB) * Udim + h * Dh;
#pragma unroll
        for (int dt = 0; dt < 4; dt++) {
            f32x4 xv = *(const f32x4*)(XpB + dt * 16 + quad * 4);
            f32x4 o = OB[dt] * invB + xv;
            bf16x4 ob;
#pragma unroll
            for (int r2 = 0; r2 < 4; r2++) {
                ob[r2] = (bf16_t)o[r2];
                s_acc += o[r2];
                ss_acc += o[r2] * o[r2];
            }
            *(bf16x4*)(RpB + dt * 16 + quad * 4) = ob;
        }
    }
    __syncthreads();

    if (grp == 0) {
        // combine + finalize A
        const float* po = cmbO + w * 1024 + lane * 16;
#pragma unroll
        for (int dt = 0; dt < 4; dt++)
            OA[dt] += *(const f32x4*)(po + dt * 4);
        lsA += cmbLS[w * 16 + l16];
        float invA = 1.0f / lsA;
        const float* XpA = X + (bS + qidxA) * Udim + h * Dh;
        bf16_t* RpA = R + (bS + qidxA) * Udim + h * Dh;
#pragma unroll
        for (int dt = 0; dt < 4; dt++) {
            f32x4 xv = *(const f32x4*)(XpA + dt * 16 + quad * 4);
            f32x4 o = OA[dt] * invA + xv;
            bf16x4 ob;
#pragma unroll
            for (int r2 = 0; r2 < 4; r2++) {
                ob[r2] = (bf16_t)o[r2];
                s_acc += o[r2];
                ss_acc += o[r2] * o[r2];
            }
            *(bf16x4*)(RpA + dt * 16 + quad * 4) = ob;
        }
    }

    // ---- LN stats reduction over all 8 waves (group1 contributes zeros)
#pragma unroll
    for (int o = 1; o < 64; o <<= 1) {
        s_acc += __shfl_xor(s_acc, o);
        ss_acc += __shfl_xor(ss_acc, o);
    }
    int w8 = tid >> 6;
    if (lane == 0) { red[w8] = s_acc; red[8 + w8] = ss_acc; }
    __syncthreads();
    if (tid == 0) {
        float s = 0.0f, ss = 0.0f;
#pragma unroll
        for (int i = 0; i < 8; i++) { s += red[i]; ss += red[8 + i]; }
        atomicAdd(&stats[b], s);
        atomicAdd(&stats[2 + b], ss);
    }
}

// ---------------------------------------------------------------- LN apply
__global__ __launch_bounds__(256)
void ln_norm(const bf16_t* __restrict__ R, const float* __restrict__ gamma,
             const float* __restrict__ beta, const float* __restrict__ stats,
             float* __restrict__ out)
{
    constexpr float invN = 1.0f / (float)PerBatch;
    float mu[2], inv[2];
#pragma unroll
    for (int b = 0; b < 2; b++) {
        float m = stats[b] * invN;
        float var = stats[2 + b] * invN - m * m;
        mu[b] = m;
        inv[b] = rsqrtf(var + 1e-5f);
    }
    int i = blockIdx.x * 256 + threadIdx.x;      // over 8-elem groups, 512K
    int f = i * 8;
    int b = f >> 21;
    int su = f & (PerBatch - 1);
    bf16x8 rv = *(const bf16x8*)(R + f);
    float4 g0 = *(const float4*)(gamma + su);
    float4 g1 = *(const float4*)(gamma + su + 4);
    float4 be0 = *(const float4*)(beta + su);
    float4 be1 = *(const float4*)(beta + su + 4);
    float4 o0, o1;
    o0.x = ((float)rv[0] - mu[b]) * inv[b] * g0.x + be0.x;
    o0.y = ((float)rv[1] - mu[b]) * inv[b] * g0.y + be0.y;
    o0.z = ((float)rv[2] - mu[b]) * inv[b] * g0.z + be0.z;
    o0.w = ((float)rv[3] - mu[b]) * inv[b] * g0.w + be0.w;
    o1.x = ((float)rv[4] - mu[b]) * inv[b] * g1.x + be1.x;
    o1.y = ((float)rv[5] - mu[b]) * inv[b] * g1.y + be1.y;
    o1.z = ((float)rv[6] - mu[b]) * inv[b] * g1.z + be1.z;
    o1.w = ((float)rv[7] - mu[b]) * inv[b] * g1.w + be1.w;
    *(float4*)(out + f) = o0;
    *(float4*)(out + f + 4) = o1;
}

// ---------------------------------------------------------------- launch
extern "C" void kernel_launch(void* const* d_in, const int* in_sizes, int n_in,
                              void* d_out, int out_size, void* d_ws, size_t ws_size,
                              hipStream_t stream)
{
    const float* X     = (const float*)d_in[0];
    const float* Wq    = (const float*)d_in[1];
    const float* bq    = (const float*)d_in[2];
    const float* Wk    = (const float*)d_in[3];
    const float* bk    = (const float*)d_in[4];
    const float* Wv    = (const float*)d_in[5];
    const float* bv    = (const float*)d_in[6];
    const float* gamma = (const float*)d_in[7];
    const float* beta  = (const float*)d_in[8];
    float* out = (float*)d_out;

    char* ws = (char*)d_ws;
    size_t off = 0;
    auto alloc = [&](size_t bytes) -> void* {
        void* p = ws + off;
        off += (bytes + 255) & ~(size_t)255;
        return p;
    };
    bf16_t* Xb = (bf16_t*)alloc((size_t)Mrows * Cdim * 2);
    bf16_t* Tq = (bf16_t*)alloc((size_t)Cdim * Udim * 2);
    bf16_t* Tk = (bf16_t*)alloc((size_t)Cdim * Udim * 2);
    bf16_t* Tv = (bf16_t*)alloc((size_t)Cdim * Udim * 2);
    f16_t*  Qb = (f16_t*)alloc((size_t)Mrows * Udim * 2);
    f16_t*  Kb = (f16_t*)alloc((size_t)Mrows * Udim * 2);
    f16_t*  Vtb = (f16_t*)alloc((size_t)Mrows * Udim * 2);
    bf16_t* Rb = (bf16_t*)alloc((size_t)Mrows * Udim * 2);
    float*  stats = (float*)alloc(4 * sizeof(float));

    prep<<<dim3(16, 16, 4), 256, 0, stream>>>(X, Wq, Wk, Wv, Xb, Tq, Tk, Tv, stats);
    gemm_qkv<<<dim3(8, 32, 3), 256, 0, stream>>>(Xb, Tq, Tk, Tv, bq, bk, bv, Qb, Kb, Vtb);
    attn17<<<dim3(512), 512, 0, stream>>>(Qb, Kb, Vtb, X, Rb, stats);
    ln_norm<<<dim3(2048), 256, 0, stream>>>(Rb, gamma, beta, stats, out);
}